// Round 6
// baseline (2973.619 us; speedup 1.0000x reference)
//
#include <hip/hip_runtime.h>
#include <math.h>

// Conv1D(k=2,F=64,relu) -> LSTM1(H=100, relu cell, seq) -> LSTM2 (last) ->
// Dense(3) -> softmax.  B=128, T=2048, T'=2047.
//
// Round-6 design:
//  * 1024 thr/block (16 waves, 4 waves/SIMD).  Round-5 (2 waves/SIMD) was
//    latency-bound: step 2900 cyc vs ~950 VALU issue; round-4 (1 wave/SIMD)
//    was exactly 2x that.  More waves + shorter chains is the lever.
//  * K-split-4 lane quads: quad owns hidden unit p; lane q dots K-quarter q
//    for ALL 4 gates (keeps LDS broadcast traffic minimal).  Weights:
//    producer 44 halves x 4 gates = 88 f16 = 44 VGPRs; consumer 52 x 4 =
//    104 f16 = 52 VGPRs -> fits 128-VGPR cap at 4 waves/SIMD.
//  * Reduction: 2 serial ds_swizzles (xor1, xor2); all quad lanes compute
//    gates+cell redundantly (bit-identical), lane q==0 writes h.
//  * Biases folded into weights via a constant-1.0 pad element in each LDS
//    x-vector (X1[164], X2[200]) -- zero extra regs or adds.
//  * Same 2-slot LDS ring + 1 barrier/step as round 5; no global staging.
//    Waves 0..6 = LSTM1 dots, wave 7 = conv, waves 8..14 = LSTM2 dots.

typedef _Float16 h2 __attribute__((ext_vector_type(2)));

#define BB 128
#define TT 2048
#define TP 2047
#define HH 100
#define G4 400
#define FF 64

#define S1 176   // X1 slot: [x(64); h1(100); 1.0@164; pad(11)]
#define S2 208   // X2 slot: [x2(100); h2(100); 1.0@200; pad(7)]

#define L22(X) X(0) X(1) X(2) X(3) X(4) X(5) X(6) X(7) X(8) X(9) X(10) \
  X(11) X(12) X(13) X(14) X(15) X(16) X(17) X(18) X(19) X(20) X(21)
#define L26(X) L22(X) X(22) X(23) X(24) X(25)

#define DWV(j) h2 wA##j, wB##j, wC##j, wD##j;

// producer combined K-vector element kk of gate column c:
// [conv-x(64); U-h(100); bias@164; 0 pad]
static __device__ __forceinline__ float wvP(const float* __restrict__ W,
                                            const float* __restrict__ U,
                                            const float* __restrict__ Bv,
                                            int c, int kk) {
    if (kk < FF)      return W[kk * G4 + c];
    if (kk < FF + HH) return U[(kk - FF) * G4 + c];
    if (kk == FF + HH) return Bv[c];
    return 0.0f;
}
// consumer: [W-x2(100); U-h2(100); bias@200; 0 pad]
static __device__ __forceinline__ float wvC(const float* __restrict__ W,
                                            const float* __restrict__ U,
                                            const float* __restrict__ Bv,
                                            int c, int kk) {
    if (kk < HH)       return W[kk * G4 + c];
    if (kk < 2 * HH)   return U[(kk - HH) * G4 + c];
    if (kk == 2 * HH)  return Bv[c];
    return 0.0f;
}

#define LWP(j) { const int kk = kb + 2 * (j); \
  wA##j = h2{(_Float16)wvP(W,U,Bv,cA,kk), (_Float16)wvP(W,U,Bv,cA,kk+1)}; \
  wB##j = h2{(_Float16)wvP(W,U,Bv,cB,kk), (_Float16)wvP(W,U,Bv,cB,kk+1)}; \
  wC##j = h2{(_Float16)wvP(W,U,Bv,cC,kk), (_Float16)wvP(W,U,Bv,cC,kk+1)}; \
  wD##j = h2{(_Float16)wvP(W,U,Bv,cD,kk), (_Float16)wvP(W,U,Bv,cD,kk+1)}; }
#define LWC(j) { const int kk = kb + 2 * (j); \
  wA##j = h2{(_Float16)wvC(W,U,Bv,cA,kk), (_Float16)wvC(W,U,Bv,cA,kk+1)}; \
  wB##j = h2{(_Float16)wvC(W,U,Bv,cB,kk), (_Float16)wvC(W,U,Bv,cB,kk+1)}; \
  wC##j = h2{(_Float16)wvC(W,U,Bv,cC,kk), (_Float16)wvC(W,U,Bv,cC,kk+1)}; \
  wD##j = h2{(_Float16)wvC(W,U,Bv,cD,kk), (_Float16)wvC(W,U,Bv,cD,kk+1)}; }

#define FD(w, x, acc) acc = __builtin_amdgcn_fdot2(w, x, acc, false)
#define B2(f) __builtin_bit_cast(h2, f)

// one float2 (4 halves) feeds chunks j0,j1 across the 4 gate accumulators
#define DD(i, j0, j1) { const float2 v = vb[i]; \
  const h2 x0 = B2(v.x), x1 = B2(v.y); \
  FD(wA##j0, x0, zA); FD(wB##j0, x0, zB); FD(wC##j0, x0, zC); FD(wD##j0, x0, zD); \
  FD(wA##j1, x1, zA); FD(wB##j1, x1, zB); FD(wC##j1, x1, zC); FD(wD##j1, x1, zD); }

#define PDOT DD(0,0,1) DD(1,2,3) DD(2,4,5) DD(3,6,7) DD(4,8,9) DD(5,10,11) \
  DD(6,12,13) DD(7,14,15) DD(8,16,17) DD(9,18,19) DD(10,20,21)
#define CDOT PDOT DD(11,22,23) DD(12,24,25)

// sum over the lane quad: xor1 then xor2 butterfly (never crosses 32-group)
static __device__ __forceinline__ float qsum(float z) {
    z += __builtin_bit_cast(float,
        __builtin_amdgcn_ds_swizzle(__builtin_bit_cast(int, z), 0x041F));
    z += __builtin_bit_cast(float,
        __builtin_amdgcn_ds_swizzle(__builtin_bit_cast(int, z), 0x081F));
    return z;
}
static __device__ __forceinline__ float sig(float z) {
    return 1.0f / (1.0f + __expf(-z));
}

__global__ __launch_bounds__(1024, 4)
void fused_lstm_kernel(const float* __restrict__ inp,     // [B,T]
                       const float* __restrict__ conv_w,  // [2,1,F]
                       const float* __restrict__ conv_b,  // [F]
                       const float* __restrict__ w1, const float* __restrict__ u1,
                       const float* __restrict__ b1,
                       const float* __restrict__ w2, const float* __restrict__ u2,
                       const float* __restrict__ b2,
                       const float* __restrict__ dw, const float* __restrict__ db,
                       float* __restrict__ out)           // [B,3]
{
    const int tid = threadIdx.x;
    const int b   = blockIdx.x;

    __shared__ float s_buf[TT];
    __shared__ __align__(16) _Float16 X1[2 * S1];
    __shared__ __align__(16) _Float16 X2[2 * S2];

    for (int i = tid; i < TT; i += 1024) s_buf[i] = inp[(size_t)b * TT + i];
    for (int i = tid; i < 2 * S1; i += 1024) X1[i] = (_Float16)0.0f;
    for (int i = tid; i < 2 * S2; i += 1024) X2[i] = (_Float16)0.0f;
    __syncthreads();                                   // (A)
    if (tid == 0) {                                    // bias-input constants
        X1[FF + HH] = (_Float16)1.0f; X1[S1 + FF + HH] = (_Float16)1.0f;
        X2[2 * HH]  = (_Float16)1.0f; X2[S2 + 2 * HH]  = (_Float16)1.0f;
    }

    if (tid < 512) {
        // ============ PRODUCER: conv (wave 7) + LSTM1 (waves 0..6) ==========
        const int rt = tid;
        const int p  = (rt < 400) ? (rt >> 2) : 0;
        const int q  = rt & 3;
        const int kb = 44 * q;                         // K-quarter base
        const int cA = p, cB = HH + p, cC = 2 * HH + p, cD = 3 * HH + p;
        const float* W = w1;
        const float* U = u1;
        const float* Bv = b1;

        L22(DWV)
        L22(LWP)

        float cw0 = 0.f, cw1 = 0.f, cb0 = 0.f;
        const int f = rt - 448;
        if (rt >= 448) {
            cw0 = conv_w[f]; cw1 = conv_w[FF + f]; cb0 = conv_b[f];
            // x(0) into slot 0
            X1[f] = (_Float16)fmaxf(fmaf(s_buf[0], cw0, fmaf(s_buf[1], cw1, cb0)), 0.f);
        }
        __syncthreads();                               // (B)

        float c = 0.0f;
        for (int t = 0; t <= TP; ++t) {
            if (t < TP) {
                const _Float16* cur = X1 + (t & 1) * S1;
                _Float16*       nx  = X1 + ((t & 1) ^ 1) * S1;
                if (rt < 400) {
                    float zA = 0.f, zB = 0.f, zC = 0.f, zD = 0.f;
                    const float2* vb = (const float2*)(cur + kb);
                    PDOT
                    const float zi = qsum(zA), zf = qsum(zB);
                    const float zg = qsum(zC), zo = qsum(zD);
                    const float gi = sig(zi), gf = sig(zf), go = sig(zo);
                    const float gg = fmaxf(zg, 0.f);
                    c = fmaf(gf, c, gi * gg);
                    const float h = go * fmaxf(c, 0.f);
                    if (q == 0) {
                        const _Float16 hq = (_Float16)h;
                        nx[FF + p] = hq;                       // h1 for LSTM1(t+1)
                        (X2 + ((t & 1) ^ 1) * S2)[p] = hq;     // x2 for LSTM2
                    }
                } else if (rt >= 448 && t + 1 < TP) {  // conv x(t+1) -> next slot
                    nx[f] = (_Float16)fmaxf(
                        fmaf(s_buf[t + 1], cw0, fmaf(s_buf[t + 2], cw1, cb0)), 0.f);
                }
            }
            __syncthreads();                           // one barrier per step
        }
    } else {
        // ============ CONSUMER: LSTM2 (waves 8..14) + dense + softmax =======
        const int rt = tid - 512;
        const int p  = (rt < 400) ? (rt >> 2) : 0;
        const int q  = rt & 3;
        const int kb = 52 * q;
        const int cA = p, cB = HH + p, cC = 2 * HH + p, cD = 3 * HH + p;
        const float* W = w2;
        const float* U = u2;
        const float* Bv = b2;

        L26(DWV)
        L26(LWC)
        __syncthreads();                               // (B)

        float c = 0.0f;
        for (int t = 0; t <= TP; ++t) {
            if (t >= 1 && rt < 400) {                  // consumer step t-1
                const _Float16* cur = X2 + (t & 1) * S2;
                float zA = 0.f, zB = 0.f, zC = 0.f, zD = 0.f;
                const float2* vb = (const float2*)(cur + kb);
                CDOT
                const float zi = qsum(zA), zf = qsum(zB);
                const float zg = qsum(zC), zo = qsum(zD);
                const float gi = sig(zi), gf = sig(zf), go = sig(zo);
                const float gg = fmaxf(zg, 0.f);
                c = fmaf(gf, c, gi * gg);
                const float h = go * fmaxf(c, 0.f);
                if (q == 0)
                    X2[((t & 1) ^ 1) * S2 + HH + p] = (_Float16)h;
            }
            __syncthreads();                           // one barrier per step
        }

        // final h2 (step TP-1) was written at iter TP into slot 0 h-region
        if (rt == 0) {
            float l[3];
#pragma unroll
            for (int a = 0; a < 3; ++a) {
                float acc = db[a];
                for (int j = 0; j < HH; ++j)
                    acc = fmaf((float)X2[HH + j], dw[j * 3 + a], acc);
                l[a] = acc;
            }
            const float m = fmaxf(l[0], fmaxf(l[1], l[2]));
            const float e0 = __expf(l[0] - m), e1 = __expf(l[1] - m), e2 = __expf(l[2] - m);
            const float inv = 1.0f / (e0 + e1 + e2);
            out[b * 3 + 0] = e0 * inv;
            out[b * 3 + 1] = e1 * inv;
            out[b * 3 + 2] = e2 * inv;
        }
    }
}

// ---------------- launch ----------------------------------------------------
extern "C" void kernel_launch(void* const* d_in, const int* in_sizes, int n_in,
                              void* d_out, int out_size, void* d_ws, size_t ws_size,
                              hipStream_t stream) {
    const float* s      = (const float*)d_in[0];
    const float* conv_w = (const float*)d_in[1];
    const float* conv_b = (const float*)d_in[2];
    const float* w1     = (const float*)d_in[3];
    const float* u1     = (const float*)d_in[4];
    const float* b1     = (const float*)d_in[5];
    const float* w2     = (const float*)d_in[6];
    const float* u2     = (const float*)d_in[7];
    const float* b2     = (const float*)d_in[8];
    const float* dw     = (const float*)d_in[9];
    const float* db     = (const float*)d_in[10];

    fused_lstm_kernel<<<BB, 1024, 0, stream>>>(
        s, conv_w, conv_b, w1, u1, b1, w2, u2, b2, dw, db, (float*)d_out);
}

// Round 7
// 2969.736 us; speedup vs baseline: 1.0013x; 1.0013x over previous
//
#include <hip/hip_runtime.h>
#include <math.h>

// Conv1D(k=2,F=64,relu) -> LSTM1(H=100, relu cell, seq) -> LSTM2 (last) ->
// Dense(3) -> softmax.  B=128, T=2048, T'=2047.
//
// Round-7 = round-6 with ONE change: __launch_bounds__(1024,2) (was (1024,4)).
// Round 6's (1024,4) capped the unified reg file at 128/wave; the allocator
// split 64 VGPR + 64 AGPR and put the dot2 weights in AGPRs (VGPR_Count=64).
// v_dot2 can't source AGPRs -> one v_accvgpr_read per weight use, doubling
// per-wave VALU issue and erasing the 4-waves/SIMD latency-hiding gain.
// (1024,2) raises the cap to 256; ~85-reg usage stays all-arch.  Occupancy
// is structurally 4 waves/SIMD either way (16-wave block, 1 block/CU).
//
// Structure (from round 6):
//  * 1024 thr/block, 1 block per batch element (128 blocks).
//  * K-split-4 lane quads: quad owns hidden unit p; lane q dots K-quarter q
//    for ALL 4 gates.  Producer 22 h2 regs/gate-chunk set (44 VGPRs),
//    consumer 26 (52 VGPRs).
//  * Reduction: xor1+xor2 ds_swizzle butterfly; all quad lanes redo the
//    cell update redundantly (bit-identical); lane q==0 writes h.
//  * Biases folded in via constant-1.0 element in the LDS x-vectors.
//  * 2-slot LDS ring between LSTM1 (waves 0..6), conv (wave 7), LSTM2
//    (waves 8..14); ONE __syncthreads per step; no global staging.

typedef _Float16 h2 __attribute__((ext_vector_type(2)));

#define BB 128
#define TT 2048
#define TP 2047
#define HH 100
#define G4 400
#define FF 64

#define S1 176   // X1 slot: [x(64); h1(100); 1.0@164; pad(11)]
#define S2 208   // X2 slot: [x2(100); h2(100); 1.0@200; pad(7)]

#define L22(X) X(0) X(1) X(2) X(3) X(4) X(5) X(6) X(7) X(8) X(9) X(10) \
  X(11) X(12) X(13) X(14) X(15) X(16) X(17) X(18) X(19) X(20) X(21)
#define L26(X) L22(X) X(22) X(23) X(24) X(25)

#define DWV(j) h2 wA##j, wB##j, wC##j, wD##j;

// producer combined K-vector element kk of gate column c:
// [conv-x(64); U-h(100); bias@164; 0 pad]
static __device__ __forceinline__ float wvP(const float* __restrict__ W,
                                            const float* __restrict__ U,
                                            const float* __restrict__ Bv,
                                            int c, int kk) {
    if (kk < FF)      return W[kk * G4 + c];
    if (kk < FF + HH) return U[(kk - FF) * G4 + c];
    if (kk == FF + HH) return Bv[c];
    return 0.0f;
}
// consumer: [W-x2(100); U-h2(100); bias@200; 0 pad]
static __device__ __forceinline__ float wvC(const float* __restrict__ W,
                                            const float* __restrict__ U,
                                            const float* __restrict__ Bv,
                                            int c, int kk) {
    if (kk < HH)       return W[kk * G4 + c];
    if (kk < 2 * HH)   return U[(kk - HH) * G4 + c];
    if (kk == 2 * HH)  return Bv[c];
    return 0.0f;
}

#define LWP(j) { const int kk = kb + 2 * (j); \
  wA##j = h2{(_Float16)wvP(W,U,Bv,cA,kk), (_Float16)wvP(W,U,Bv,cA,kk+1)}; \
  wB##j = h2{(_Float16)wvP(W,U,Bv,cB,kk), (_Float16)wvP(W,U,Bv,cB,kk+1)}; \
  wC##j = h2{(_Float16)wvP(W,U,Bv,cC,kk), (_Float16)wvP(W,U,Bv,cC,kk+1)}; \
  wD##j = h2{(_Float16)wvP(W,U,Bv,cD,kk), (_Float16)wvP(W,U,Bv,cD,kk+1)}; }
#define LWC(j) { const int kk = kb + 2 * (j); \
  wA##j = h2{(_Float16)wvC(W,U,Bv,cA,kk), (_Float16)wvC(W,U,Bv,cA,kk+1)}; \
  wB##j = h2{(_Float16)wvC(W,U,Bv,cB,kk), (_Float16)wvC(W,U,Bv,cB,kk+1)}; \
  wC##j = h2{(_Float16)wvC(W,U,Bv,cC,kk), (_Float16)wvC(W,U,Bv,cC,kk+1)}; \
  wD##j = h2{(_Float16)wvC(W,U,Bv,cD,kk), (_Float16)wvC(W,U,Bv,cD,kk+1)}; }

#define FD(w, x, acc) acc = __builtin_amdgcn_fdot2(w, x, acc, false)
#define B2(f) __builtin_bit_cast(h2, f)

// one float2 (4 halves) feeds chunks j0,j1 across the 4 gate accumulators
#define DD(i, j0, j1) { const float2 v = vb[i]; \
  const h2 x0 = B2(v.x), x1 = B2(v.y); \
  FD(wA##j0, x0, zA); FD(wB##j0, x0, zB); FD(wC##j0, x0, zC); FD(wD##j0, x0, zD); \
  FD(wA##j1, x1, zA); FD(wB##j1, x1, zB); FD(wC##j1, x1, zC); FD(wD##j1, x1, zD); }

#define PDOT DD(0,0,1) DD(1,2,3) DD(2,4,5) DD(3,6,7) DD(4,8,9) DD(5,10,11) \
  DD(6,12,13) DD(7,14,15) DD(8,16,17) DD(9,18,19) DD(10,20,21)
#define CDOT PDOT DD(11,22,23) DD(12,24,25)

// sum over the lane quad: xor1 then xor2 butterfly (never crosses 32-group)
static __device__ __forceinline__ float qsum(float z) {
    z += __builtin_bit_cast(float,
        __builtin_amdgcn_ds_swizzle(__builtin_bit_cast(int, z), 0x041F));
    z += __builtin_bit_cast(float,
        __builtin_amdgcn_ds_swizzle(__builtin_bit_cast(int, z), 0x081F));
    return z;
}
static __device__ __forceinline__ float sig(float z) {
    return 1.0f / (1.0f + __expf(-z));
}

__global__ __launch_bounds__(1024, 2)
void fused_lstm_kernel(const float* __restrict__ inp,     // [B,T]
                       const float* __restrict__ conv_w,  // [2,1,F]
                       const float* __restrict__ conv_b,  // [F]
                       const float* __restrict__ w1, const float* __restrict__ u1,
                       const float* __restrict__ b1,
                       const float* __restrict__ w2, const float* __restrict__ u2,
                       const float* __restrict__ b2,
                       const float* __restrict__ dw, const float* __restrict__ db,
                       float* __restrict__ out)           // [B,3]
{
    const int tid = threadIdx.x;
    const int b   = blockIdx.x;

    __shared__ float s_buf[TT];
    __shared__ __align__(16) _Float16 X1[2 * S1];
    __shared__ __align__(16) _Float16 X2[2 * S2];

    for (int i = tid; i < TT; i += 1024) s_buf[i] = inp[(size_t)b * TT + i];
    for (int i = tid; i < 2 * S1; i += 1024) X1[i] = (_Float16)0.0f;
    for (int i = tid; i < 2 * S2; i += 1024) X2[i] = (_Float16)0.0f;
    __syncthreads();                                   // (A)
    if (tid == 0) {                                    // bias-input constants
        X1[FF + HH] = (_Float16)1.0f; X1[S1 + FF + HH] = (_Float16)1.0f;
        X2[2 * HH]  = (_Float16)1.0f; X2[S2 + 2 * HH]  = (_Float16)1.0f;
    }

    if (tid < 512) {
        // ============ PRODUCER: conv (wave 7) + LSTM1 (waves 0..6) ==========
        const int rt = tid;
        const int p  = (rt < 400) ? (rt >> 2) : 0;
        const int q  = rt & 3;
        const int kb = 44 * q;                         // K-quarter base
        const int cA = p, cB = HH + p, cC = 2 * HH + p, cD = 3 * HH + p;
        const float* W = w1;
        const float* U = u1;
        const float* Bv = b1;

        L22(DWV)
        L22(LWP)

        float cw0 = 0.f, cw1 = 0.f, cb0 = 0.f;
        const int f = rt - 448;
        if (rt >= 448) {
            cw0 = conv_w[f]; cw1 = conv_w[FF + f]; cb0 = conv_b[f];
            // x(0) into slot 0
            X1[f] = (_Float16)fmaxf(fmaf(s_buf[0], cw0, fmaf(s_buf[1], cw1, cb0)), 0.f);
        }
        __syncthreads();                               // (B)

        float c = 0.0f;
        for (int t = 0; t <= TP; ++t) {
            if (t < TP) {
                const _Float16* cur = X1 + (t & 1) * S1;
                _Float16*       nx  = X1 + ((t & 1) ^ 1) * S1;
                if (rt < 400) {
                    float zA = 0.f, zB = 0.f, zC = 0.f, zD = 0.f;
                    const float2* vb = (const float2*)(cur + kb);
                    PDOT
                    const float zi = qsum(zA), zf = qsum(zB);
                    const float zg = qsum(zC), zo = qsum(zD);
                    const float gi = sig(zi), gf = sig(zf), go = sig(zo);
                    const float gg = fmaxf(zg, 0.f);
                    c = fmaf(gf, c, gi * gg);
                    const float h = go * fmaxf(c, 0.f);
                    if (q == 0) {
                        const _Float16 hq = (_Float16)h;
                        nx[FF + p] = hq;                       // h1 for LSTM1(t+1)
                        (X2 + ((t & 1) ^ 1) * S2)[p] = hq;     // x2 for LSTM2
                    }
                } else if (rt >= 448 && t + 1 < TP) {  // conv x(t+1) -> next slot
                    nx[f] = (_Float16)fmaxf(
                        fmaf(s_buf[t + 1], cw0, fmaf(s_buf[t + 2], cw1, cb0)), 0.f);
                }
            }
            __syncthreads();                           // one barrier per step
        }
    } else {
        // ============ CONSUMER: LSTM2 (waves 8..14) + dense + softmax =======
        const int rt = tid - 512;
        const int p  = (rt < 400) ? (rt >> 2) : 0;
        const int q  = rt & 3;
        const int kb = 52 * q;
        const int cA = p, cB = HH + p, cC = 2 * HH + p, cD = 3 * HH + p;
        const float* W = w2;
        const float* U = u2;
        const float* Bv = b2;

        L26(DWV)
        L26(LWC)
        __syncthreads();                               // (B)

        float c = 0.0f;
        for (int t = 0; t <= TP; ++t) {
            if (t >= 1 && rt < 400) {                  // consumer step t-1
                const _Float16* cur = X2 + (t & 1) * S2;
                float zA = 0.f, zB = 0.f, zC = 0.f, zD = 0.f;
                const float2* vb = (const float2*)(cur + kb);
                CDOT
                const float zi = qsum(zA), zf = qsum(zB);
                const float zg = qsum(zC), zo = qsum(zD);
                const float gi = sig(zi), gf = sig(zf), go = sig(zo);
                const float gg = fmaxf(zg, 0.f);
                c = fmaf(gf, c, gi * gg);
                const float h = go * fmaxf(c, 0.f);
                if (q == 0)
                    X2[((t & 1) ^ 1) * S2 + HH + p] = (_Float16)h;
            }
            __syncthreads();                           // one barrier per step
        }

        // final h2 (step TP-1) was written at iter TP into slot 0 h-region
        if (rt == 0) {
            float l[3];
#pragma unroll
            for (int a = 0; a < 3; ++a) {
                float acc = db[a];
                for (int j = 0; j < HH; ++j)
                    acc = fmaf((float)X2[HH + j], dw[j * 3 + a], acc);
                l[a] = acc;
            }
            const float m = fmaxf(l[0], fmaxf(l[1], l[2]));
            const float e0 = __expf(l[0] - m), e1 = __expf(l[1] - m), e2 = __expf(l[2] - m);
            const float inv = 1.0f / (e0 + e1 + e2);
            out[b * 3 + 0] = e0 * inv;
            out[b * 3 + 1] = e1 * inv;
            out[b * 3 + 2] = e2 * inv;
        }
    }
}

// ---------------- launch ----------------------------------------------------
extern "C" void kernel_launch(void* const* d_in, const int* in_sizes, int n_in,
                              void* d_out, int out_size, void* d_ws, size_t ws_size,
                              hipStream_t stream) {
    const float* s      = (const float*)d_in[0];
    const float* conv_w = (const float*)d_in[1];
    const float* conv_b = (const float*)d_in[2];
    const float* w1     = (const float*)d_in[3];
    const float* u1     = (const float*)d_in[4];
    const float* b1     = (const float*)d_in[5];
    const float* w2     = (const float*)d_in[6];
    const float* u2     = (const float*)d_in[7];
    const float* b2     = (const float*)d_in[8];
    const float* dw     = (const float*)d_in[9];
    const float* db     = (const float*)d_in[10];

    fused_lstm_kernel<<<BB, 1024, 0, stream>>>(
        s, conv_w, conv_b, w1, u1, b1, w2, u2, b2, dw, db, (float*)d_out);
}